// Round 18
// baseline (53.499 us; speedup 1.0000x reference)
//
#include <hip/hip_runtime.h>
#include <stdint.h>

#define BSZ 4096
#define LSEQ 1024

typedef _Float16 half8 __attribute__((ext_vector_type(8)));
typedef __fp16 fp16x2 __attribute__((ext_vector_type(2)));
typedef float f32x4 __attribute__((ext_vector_type(4)));

union S8 { int i[4]; half8 h; int4 q; };

__device__ __forceinline__ int pack_f16(float a, float b) {
    union { _Float16 h[2]; int i; } u;
    u.h[0] = (_Float16)a;          // v_cvt_f16_f32 (RNE)
    u.h[1] = (_Float16)b;
    return u.i;                    // v_pack_b32_f16
}
// RTZ pack then packed f16 relu: v_cvt_pkrtz_f16_f32 + v_pk_max_f16 (2 VALU)
__device__ __forceinline__ int relu_pkrtz(float a, float b) {
    fp16x2 h = __builtin_amdgcn_cvt_pkrtz(a, b);
    h = __builtin_elementwise_max(h, (fp16x2)0.f);
    union { fp16x2 v; int i; } u;
    u.v = h;
    return u.i;
}
// (a,b) -> hi dword [f16(b)|f16(a)], lo dword [f16(b-bh)|f16(a-ah)]
__device__ __forceinline__ void split_pair_f16(float a, float b, int& dh, int& dl) {
    _Float16 ah = (_Float16)a, bh = (_Float16)b;
    float al = a - (float)ah, bl = b - (float)bh;
    union { _Float16 h[2]; int i; } uh, ul;
    uh.h[0] = ah; uh.h[1] = bh;
    ul.h[0] = (_Float16)al; ul.h[1] = (_Float16)bl;
    dh = uh.i; dl = ul.i;
}
__device__ __forceinline__ f32x4 MFMA(half8 a, half8 b, f32x4 c) {
    return __builtin_amdgcn_mfma_f32_16x16x32_f16(a, b, c, 0, 0, 0);
}

// ws layout (int units):
//   int4 slots 0..13   : A fragments [f][lane]   (14*64*4 = 3584 ints)
//   WS_EMBH + app      : embedding hi dword (f16 e0,e1)
//   WS_EMBL + app      : embedding lo dword
//   WS_EMBR + i        : raw normalized embedding floats [10][2]
#define WS_EMBH 5376
#define WS_EMBL 5392
#define WS_EMBR 5408

__global__ void sp_prep(const float* __restrict__ emb,
                        const float* __restrict__ fW1, const float* __restrict__ fb1,
                        const float* __restrict__ fW2, const float* __restrict__ fb2,
                        const float* __restrict__ fW3, const float* __restrict__ fb3,
                        int* __restrict__ ws)
{
    const int lane = threadIdx.x;          // 64 threads, 1 wave
    const int L = lane & 15, g = lane >> 4;
    int4* wf = (int4*)ws;

    // ---- A1: one frag per mt; A 2-term f16 packed along K ----
    // B1 supplies (all lanes): [d_eh, d_l, d_el, ones]; A zero for g>=2.
    // bias1_ext: j1<50 -> fb1[j1]; j1==63 -> 1.0 (ones row for GEMM2 bias)
    #pragma unroll
    for (int mt = 0; mt < 4; ++mt) {
        int j1 = ((mt >> 1) << 5) + ((L >> 2) << 3) + ((mt & 1) << 2) + (L & 3);
        float wv[4];
        _Float16 ah[4]; float alv[4];
        #pragma unroll
        for (int c = 0; c < 4; ++c) {
            wv[c] = (j1 < 50) ? fW1[c * 50 + j1] : 0.f;
            ah[c] = (_Float16)wv[c];
            alv[c] = wv[c] - (float)ah[c];
        }
        float bb = (j1 < 50) ? fb1[j1] : (j1 == 63 ? 1.f : 0.f);
        _Float16 bh = (_Float16)bb;
        float blv = bb - (float)bh;
        _Float16 v[8];
        #pragma unroll
        for (int e = 0; e < 8; ++e) {
            _Float16 x = (_Float16)0.f;
            if (g == 0) {
                if (e < 4) x = ah[e];
                else if (e < 6) x = ah[e - 4];
                else if (e == 6) x = bh;
            } else if (g == 1) {
                if (e < 4) x = (_Float16)alv[e];
                else if (e < 6) x = (_Float16)alv[e - 4];
                else if (e == 6) x = (_Float16)blv;
            }
            v[e] = x;
        }
        S8 F;
        #pragma unroll
        for (int d = 0; d < 4; ++d) {
            union { _Float16 h[2]; int i; } u;
            u.h[0] = v[2 * d]; u.h[1] = v[2 * d + 1];
            F.i[d] = u.i;
        }
        wf[mt * 64 + lane] = F.q;
    }

    // ---- A2 Ah/Al frags (sigma2 row permutation; f16 2-term) ----
    // row j1v==63 carries bias2 (h1[63]==1): j2<25 -> fb2[j2]; j2==31 -> 1.0
    #pragma unroll
    for (int kt = 0; kt < 2; ++kt) {
        #pragma unroll
        for (int mt2 = 0; mt2 < 2; ++mt2) {
            int j2 = ((L >> 2) << 3) + (mt2 << 2) + (L & 3);
            float w[8];
            #pragma unroll
            for (int r = 0; r < 8; ++r) {
                int j1v = kt * 32 + 8 * g + r;
                float wv = 0.f;
                if (j1v < 50)       wv = (j2 < 25) ? fW2[j1v * 25 + j2] : 0.f;
                else if (j1v == 63) wv = (j2 < 25) ? fb2[j2] : (j2 == 31 ? 1.f : 0.f);
                w[r] = wv;
            }
            S8 H, Lo;
            #pragma unroll
            for (int d = 0; d < 4; ++d) split_pair_f16(w[2*d], w[2*d+1], H.i[d], Lo.i[d]);
            wf[(4 + kt * 2 + mt2) * 64 + lane] = H.q;
            wf[(8 + kt * 2 + mt2) * 64 + lane] = Lo.q;
        }
    }

    // ---- A3 Ah/Al frags ----
    // row j2v==31 carries bias3 (h2[31]==1): m<5 -> fb3[m]
    {
        int m = L;
        float w[8];
        #pragma unroll
        for (int r = 0; r < 8; ++r) {
            int j2v = 8 * g + r;
            float wv = 0.f;
            if (j2v < 25)       wv = (m < 5) ? fW3[j2v * 5 + m] : 0.f;
            else if (j2v == 31) wv = (m < 5) ? fb3[m] : 0.f;
            w[r] = wv;
        }
        S8 H, Lo;
        #pragma unroll
        for (int d = 0; d < 4; ++d) split_pair_f16(w[2*d], w[2*d+1], H.i[d], Lo.i[d]);
        wf[12 * 64 + lane] = H.q;
        wf[13 * 64 + lane] = Lo.q;
    }

    // ---- renormalized embedding: raw floats + f16 hi/lo dwords ----
    if (lane < 10) {
        float a0 = emb[2 * lane], a1 = emb[2 * lane + 1];
        float n = sqrtf(a0 * a0 + a1 * a1);
        float s = fminf(1.f, 1.f / fmaxf(n, 1e-7f));
        float e0 = a0 * s, e1 = a1 * s;
        int dh, dl;
        split_pair_f16(e0, e1, dh, dl);
        ws[WS_EMBH + lane] = dh;
        ws[WS_EMBL + lane] = dl;
        ((float*)ws)[WS_EMBR + 2 * lane] = e0;
        ((float*)ws)[WS_EMBR + 2 * lane + 1] = e1;
    }
}

// Two batch rows per block: waves 0,1 -> row0; waves 2,3 -> row1.
// B1 frags stored as 12B (3 dwords); dword3 (ones) is an immediate.
__global__ __launch_bounds__(256, 4) void sp_main(
    const float* __restrict__ x_features,
    const float* __restrict__ features,
    const int* __restrict__ ws,
    const float* __restrict__ rW1, const float* __restrict__ rb1,
    const float* __restrict__ rW2, const float* __restrict__ rb2,
    const float* __restrict__ rW3, const float* __restrict__ rb3,
    float* __restrict__ out)
{
    __shared__ int2 embhl[16];
    __shared__ float embr[20];
    __shared__ int bs3[2][3 * LSEQ];     // 12B/frag; lane stride 3 dwords -> conflict-free
    __shared__ float redS[4][5], redM[4][5];
    __shared__ float hhs[2][14];
    __shared__ float r1buf[2][50];

    const int t = threadIdx.x;
    const int b = blockIdx.x;            // handles batch rows 2b, 2b+1
    const int lane = t & 63;
    const int wid = t >> 6;
    const int L = lane & 15;

    // ---- load prepacked A fragments (L2-broadcast); biases ride in A/B k-slots ----
    const int4* wf = (const int4*)ws;
    S8 A1[4], A2H[4], A2L[4], A3H, A3L;
    #pragma unroll
    for (int f = 0; f < 4; ++f)  A1[f].q  = wf[f * 64 + lane];
    #pragma unroll
    for (int f = 0; f < 4; ++f)  A2H[f].q = wf[(4 + f) * 64 + lane];
    #pragma unroll
    for (int f = 0; f < 4; ++f)  A2L[f].q = wf[(8 + f) * 64 + lane];
    A3H.q = wf[12 * 64 + lane];
    A3L.q = wf[13 * 64 + lane];

    if (t < 16) { embhl[t] = make_int2(ws[WS_EMBH + t], ws[WS_EMBL + t]); }
    if (t < 20) embr[t] = ((const float*)ws)[WS_EMBR + t];
    __syncthreads();

    // ---- stage BOTH rows' inputs as 12B B1 frags ----
    // thread t handles positions {t, t+256, t+512, t+768}; writes stride 3 dwords.
    const float* f0 = features + (size_t)(2 * b) * (3 * LSEQ);
    #pragma unroll
    for (int r = 0; r < 2; ++r) {
        const float* fr = f0 + r * 3 * LSEQ;
        #pragma unroll
        for (int j = 0; j < 4; ++j) {
            const int p = t + 256 * j;
            float av = fr[p];
            float bv = fr[LSEQ + p];
            float cv = fr[2 * LSEQ + p];
            int2 e = embhl[(int)av];
            int* q = &bs3[r][3 * p];
            q[0] = e.x;
            q[1] = pack_f16(bv, cv);
            q[2] = e.y;
        }
    }
    __syncthreads();

    float rs[4] = {0.f, 0.f, 0.f, 0.f};
    float rm[4] = {-3.4e38f, -3.4e38f, -3.4e38f, -3.4e38f};
    const f32x4 kzero = {0.f, 0.f, 0.f, 0.f};

    const int wr = wid >> 1;            // this wave's row
    const int hw = wid & 1;             // which half of the row
    const int pbase = hw * 512 + L;

    // ---- dual-tile main loop: chains = tiles it and it+16 of this wave's half ----
    #pragma unroll 2
    for (int it = 0; it < 16; ++it) {
        const int* qa = &bs3[wr][3 * (pbase + it * 16)];
        const int* qb = qa + 3 * 256;
        S8 B1a, B1b;
        B1a.i[0] = qa[0]; B1a.i[1] = qa[1]; B1a.i[2] = qa[2]; B1a.i[3] = 0x00003C00;
        B1b.i[0] = qb[0]; B1b.i[1] = qb[1]; B1b.i[2] = qb[2]; B1b.i[3] = 0x00003C00;

        // GEMM1 (both chains): 4+4 independent MFMAs
        f32x4 h1a[4], h1b[4];
        #pragma unroll
        for (int mt = 0; mt < 4; ++mt) h1a[mt] = MFMA(A1[mt].h, B1a.h, kzero);
        #pragma unroll
        for (int mt = 0; mt < 4; ++mt) h1b[mt] = MFMA(A1[mt].h, B1b.h, kzero);

        // pack chain A (VALU) overlaps chain B's MFMA completion
        S8 B20a, B21a;
        B20a.i[0] = relu_pkrtz(h1a[0][0], h1a[0][1]);
        B20a.i[1] = relu_pkrtz(h1a[0][2], h1a[0][3]);
        B20a.i[2] = relu_pkrtz(h1a[1][0], h1a[1][1]);
        B20a.i[3] = relu_pkrtz(h1a[1][2], h1a[1][3]);
        B21a.i[0] = relu_pkrtz(h1a[2][0], h1a[2][1]);
        B21a.i[1] = relu_pkrtz(h1a[2][2], h1a[2][3]);
        B21a.i[2] = relu_pkrtz(h1a[3][0], h1a[3][1]);
        B21a.i[3] = relu_pkrtz(h1a[3][2], h1a[3][3]);

        // GEMM2 chain A
        f32x4 h2a[2];
        #pragma unroll
        for (int mt2 = 0; mt2 < 2; ++mt2) {
            f32x4 acc = kzero;
            acc = MFMA(A2H[mt2].h,     B20a.h, acc);
            acc = MFMA(A2L[mt2].h,     B20a.h, acc);
            acc = MFMA(A2H[2 + mt2].h, B21a.h, acc);
            acc = MFMA(A2L[2 + mt2].h, B21a.h, acc);
            h2a[mt2] = acc;
        }

        // pack chain B (VALU) overlaps chain A's GEMM2
        S8 B20b, B21b;
        B20b.i[0] = relu_pkrtz(h1b[0][0], h1b[0][1]);
        B20b.i[1] = relu_pkrtz(h1b[0][2], h1b[0][3]);
        B20b.i[2] = relu_pkrtz(h1b[1][0], h1b[1][1]);
        B20b.i[3] = relu_pkrtz(h1b[1][2], h1b[1][3]);
        B21b.i[0] = relu_pkrtz(h1b[2][0], h1b[2][1]);
        B21b.i[1] = relu_pkrtz(h1b[2][2], h1b[2][3]);
        B21b.i[2] = relu_pkrtz(h1b[3][0], h1b[3][1]);
        B21b.i[3] = relu_pkrtz(h1b[3][2], h1b[3][3]);

        // GEMM2 chain B
        f32x4 h2b[2];
        #pragma unroll
        for (int mt2 = 0; mt2 < 2; ++mt2) {
            f32x4 acc = kzero;
            acc = MFMA(A2H[mt2].h,     B20b.h, acc);
            acc = MFMA(A2L[mt2].h,     B20b.h, acc);
            acc = MFMA(A2H[2 + mt2].h, B21b.h, acc);
            acc = MFMA(A2L[2 + mt2].h, B21b.h, acc);
            h2b[mt2] = acc;
        }

        // pack + GEMM3 chain A
        S8 B3a;
        B3a.i[0] = relu_pkrtz(h2a[0][0], h2a[0][1]);
        B3a.i[1] = relu_pkrtz(h2a[0][2], h2a[0][3]);
        B3a.i[2] = relu_pkrtz(h2a[1][0], h2a[1][1]);
        B3a.i[3] = relu_pkrtz(h2a[1][2], h2a[1][3]);
        f32x4 h3a = MFMA(A3H.h, B3a.h, kzero);
        h3a = MFMA(A3L.h, B3a.h, h3a);

        // pack + GEMM3 chain B
        S8 B3b;
        B3b.i[0] = relu_pkrtz(h2b[0][0], h2b[0][1]);
        B3b.i[1] = relu_pkrtz(h2b[0][2], h2b[0][3]);
        B3b.i[2] = relu_pkrtz(h2b[1][0], h2b[1][1]);
        B3b.i[3] = relu_pkrtz(h2b[1][2], h2b[1][3]);
        f32x4 h3b = MFMA(A3H.h, B3b.h, kzero);
        h3b = MFMA(A3L.h, B3b.h, h3b);

        #pragma unroll
        for (int r = 0; r < 4; ++r) {
            rs[r] += h3a[r] + h3b[r];
            rm[r] = fmaxf(rm[r], fmaxf(h3a[r], h3b[r]));
        }
    }

    // ---- reduce over the 16 position-lanes within each 16-lane group ----
    #pragma unroll
    for (int off = 1; off <= 8; off <<= 1) {
        #pragma unroll
        for (int r = 0; r < 4; ++r) {
            rs[r] += __shfl_xor(rs[r], off);
            rm[r] = fmaxf(rm[r], __shfl_xor(rm[r], off));
        }
    }
    {
        const int kg = (lane >> 4);
        if (L == 0) {
            #pragma unroll
            for (int r = 0; r < 4; ++r) {
                int m = 4 * kg + r;
                if (m < 5) { redS[wid][m] = rs[r]; redM[wid][m] = rm[r]; }
            }
        }
    }
    __syncthreads();

    // ---- combine waves per row + build hh[2][14] ----
    if (t < 5) {
        hhs[0][t] = redS[0][t] + redS[1][t];
    } else if (t < 10) {
        hhs[0][t] = fmaxf(redM[0][t - 5], redM[1][t - 5]);
    } else if (t == 10) {
        int xa = (int)x_features[6 * b];
        hhs[0][10] = embr[2 * xa];
        hhs[0][11] = embr[2 * xa + 1];
        hhs[0][12] = x_features[6 * b + 1];
        hhs[0][13] = x_features[6 * b + 2];
    } else if (t >= 128 && t < 133) {
        hhs[1][t - 128] = redS[2][t - 128] + redS[3][t - 128];
    } else if (t >= 133 && t < 138) {
        hhs[1][t - 128] = fmaxf(redM[2][t - 133], redM[3][t - 133]);
    } else if (t == 138) {
        int xa = (int)x_features[6 * b + 3];
        hhs[1][10] = embr[2 * xa];
        hhs[1][11] = embr[2 * xa + 1];
        hhs[1][12] = x_features[6 * b + 4];
        hhs[1][13] = x_features[6 * b + 5];
    }
    __syncthreads();

    // ---- head MLPs in parallel: wave 0 -> row0, wave 2 -> row1 ----
    if (t < 50) {
        float acc = rb1[t];
        #pragma unroll
        for (int i = 0; i < 14; ++i) acc += hhs[0][i] * rW1[i * 50 + t];
        r1buf[0][t] = fmaxf(acc, 0.f);
    } else if (t >= 128 && t < 178) {
        int tt = t - 128;
        float acc = rb1[tt];
        #pragma unroll
        for (int i = 0; i < 14; ++i) acc += hhs[1][i] * rW1[i * 50 + tt];
        r1buf[1][tt] = fmaxf(acc, 0.f);
    }
    __syncthreads();

    float oacc = 0.f;
    if (t < 25) {
        float acc = rb2[t];
        #pragma unroll
        for (int k = 0; k < 50; ++k) acc += r1buf[0][k] * rW2[k * 25 + t];
        oacc = fmaxf(acc, 0.f) * rW3[t];
    } else if (t >= 128 && t < 153) {
        int tt = t - 128;
        float acc = rb2[tt];
        #pragma unroll
        for (int k = 0; k < 50; ++k) acc += r1buf[1][k] * rW2[k * 25 + tt];
        oacc = fmaxf(acc, 0.f) * rW3[tt];
    }
    if (t < 64 || (t >= 128 && t < 192)) {
        #pragma unroll
        for (int off = 32; off > 0; off >>= 1) oacc += __shfl_down(oacc, off);
    }
    if (t == 0)   out[2 * b]     = oacc + rb3[0];
    if (t == 128) out[2 * b + 1] = oacc + rb3[0];
}

extern "C" void kernel_launch(void* const* d_in, const int* in_sizes, int n_in,
                              void* d_out, int out_size, void* d_ws, size_t ws_size,
                              hipStream_t stream) {
    const float* x_features = (const float*)d_in[0];
    const float* features   = (const float*)d_in[1];
    // d_in[2] = lengths (dead in the math)
    const float* emb = (const float*)d_in[3];
    const float* fW1 = (const float*)d_in[4];
    const float* fb1 = (const float*)d_in[5];
    const float* fW2 = (const float*)d_in[6];
    const float* fb2 = (const float*)d_in[7];
    const float* fW3 = (const float*)d_in[8];
    const float* fb3 = (const float*)d_in[9];
    const float* rW1 = (const float*)d_in[10];
    const float* rb1 = (const float*)d_in[11];
    const float* rW2 = (const float*)d_in[12];
    const float* rb2 = (const float*)d_in[13];
    const float* rW3 = (const float*)d_in[14];
    const float* rb3 = (const float*)d_in[15];
    float* out = (float*)d_out;
    int* ws = (int*)d_ws;

    sp_prep<<<1, 64, 0, stream>>>(emb, fW1, fb1, fW2, fb2, fW3, fb3, ws);
    sp_main<<<BSZ / 2, 256, 0, stream>>>(x_features, features, ws,
                                         rW1, rb1, rW2, rb2, rW3, rb3, out);
}

// Round 19
// 52.811 us; speedup vs baseline: 1.0130x; 1.0130x over previous
//
#include <hip/hip_runtime.h>
#include <stdint.h>

#define BSZ 4096
#define LSEQ 1024

#if __has_builtin(__builtin_amdgcn_mfma_f32_16x16x16f16)
#define HAVE_MFMA16 1
#else
#define HAVE_MFMA16 0
#endif

typedef _Float16 half8 __attribute__((ext_vector_type(8)));
typedef _Float16 half4 __attribute__((ext_vector_type(4)));
typedef __fp16 fp16x2 __attribute__((ext_vector_type(2)));
typedef float f32x4 __attribute__((ext_vector_type(4)));

union S8 { int i[4]; half8 h; int4 q; };
union S4 { int i[2]; half4 h; int2 q; };

__device__ __forceinline__ int pack_f16(float a, float b) {
    union { _Float16 h[2]; int i; } u;
    u.h[0] = (_Float16)a;          // v_cvt_f16_f32 (RNE)
    u.h[1] = (_Float16)b;
    return u.i;                    // v_pack_b32_f16
}
// RTZ pack then packed f16 relu: v_cvt_pkrtz_f16_f32 + v_pk_max_f16 (2 VALU)
__device__ __forceinline__ int relu_pkrtz(float a, float b) {
    fp16x2 h = __builtin_amdgcn_cvt_pkrtz(a, b);
    h = __builtin_elementwise_max(h, (fp16x2)0.f);
    union { fp16x2 v; int i; } u;
    u.v = h;
    return u.i;
}
// (a,b) -> hi dword [f16(b)|f16(a)], lo dword [f16(b-bh)|f16(a-ah)]
__device__ __forceinline__ void split_pair_f16(float a, float b, int& dh, int& dl) {
    _Float16 ah = (_Float16)a, bh = (_Float16)b;
    float al = a - (float)ah, bl = b - (float)bh;
    union { _Float16 h[2]; int i; } uh, ul;
    uh.h[0] = ah; uh.h[1] = bh;
    ul.h[0] = (_Float16)al; ul.h[1] = (_Float16)bl;
    dh = uh.i; dl = ul.i;
}
__device__ __forceinline__ f32x4 MFMA(half8 a, half8 b, f32x4 c) {
    return __builtin_amdgcn_mfma_f32_16x16x32_f16(a, b, c, 0, 0, 0);
}
#if HAVE_MFMA16
__device__ __forceinline__ f32x4 MFMA16(half4 a, half4 b, f32x4 c) {
    return __builtin_amdgcn_mfma_f32_16x16x16f16(a, b, c, 0, 0, 0);
}
#endif

// ws layout (int units):
//   A1 frags: HAVE_MFMA16 ? int2 slots [mt*64+lane] (ints 0..511)
//                          : int4 slots 0..3
//   int4 slots 4..13   : A2H/A2L/A3 frags [f][lane]
//   WS_EMBH + app      : embedding hi dword (f16 e0,e1)
//   WS_EMBL + app      : embedding lo dword
//   WS_EMBR + i        : raw normalized embedding floats [10][2]
#define WS_EMBH 5376
#define WS_EMBL 5392
#define WS_EMBR 5408

__global__ void sp_prep(const float* __restrict__ emb,
                        const float* __restrict__ fW1, const float* __restrict__ fb1,
                        const float* __restrict__ fW2, const float* __restrict__ fb2,
                        const float* __restrict__ fW3, const float* __restrict__ fb3,
                        int* __restrict__ ws)
{
    const int lane = threadIdx.x;          // 64 threads, 1 wave
    const int L = lane & 15, g = lane >> 4;
    int4* wf = (int4*)ws;

    // ---- A1 fragments ----
    // sigma1 row permutation (verified r3..r18): j1 = 32*(mt>>1)+8*(L>>2)+4*(mt&1)+(L&3)
    // bias1_ext: j1<50 -> fb1[j1]; j1==63 -> 1.0 (ones row feeding GEMM2's bias row)
    #pragma unroll
    for (int mt = 0; mt < 4; ++mt) {
        int j1 = ((mt >> 1) << 5) + ((L >> 2) << 3) + ((mt & 1) << 2) + (L & 3);
        float wv[4];
        _Float16 ah[4]; float alv[4];
        #pragma unroll
        for (int c = 0; c < 4; ++c) {
            wv[c] = (j1 < 50) ? fW1[c * 50 + j1] : 0.f;
            ah[c] = (_Float16)wv[c];
            alv[c] = wv[c] - (float)ah[c];
        }
        float bb = (j1 < 50) ? fb1[j1] : (j1 == 63 ? 1.f : 0.f);
        _Float16 bh = (_Float16)bb;
        float blv = bb - (float)bh;
#if HAVE_MFMA16
        // K=16 layout: k = 4g+e. B pairing: g even -> [eh0,eh1,l0,l1]; g odd -> [el0,el1,1,0]
        _Float16 v[4];
        if (g == 0)      { v[0] = ah[0]; v[1] = ah[1]; v[2] = ah[2]; v[3] = ah[3]; }
        else if (g == 1) { v[0] = ah[0]; v[1] = ah[1]; v[2] = bh;   v[3] = (_Float16)0.f; }
        else if (g == 2) { v[0] = (_Float16)alv[0]; v[1] = (_Float16)alv[1];
                           v[2] = (_Float16)alv[2]; v[3] = (_Float16)alv[3]; }
        else             { v[0] = (_Float16)blv * (_Float16)0.f + (_Float16)alv[0]; // alv[0]
                           v[1] = (_Float16)alv[1]; v[2] = (_Float16)blv; v[3] = (_Float16)0.f; }
        S4 F;
        {
            union { _Float16 h[2]; int i; } u;
            u.h[0] = v[0]; u.h[1] = v[1]; F.i[0] = u.i;
            u.h[0] = v[2]; u.h[1] = v[3]; F.i[1] = u.i;
        }
        ((int2*)ws)[mt * 64 + lane] = F.q;
#else
        // K=32 layout (r18-verified): k = 8g+e; g0 hi terms, g1 lo terms, g2/g3 zero
        _Float16 v[8];
        #pragma unroll
        for (int e = 0; e < 8; ++e) {
            _Float16 x = (_Float16)0.f;
            if (g == 0) {
                if (e < 4) x = ah[e];
                else if (e < 6) x = ah[e - 4];
                else if (e == 6) x = bh;
            } else if (g == 1) {
                if (e < 4) x = (_Float16)alv[e];
                else if (e < 6) x = (_Float16)alv[e - 4];
                else if (e == 6) x = (_Float16)blv;
            }
            v[e] = x;
        }
        S8 F;
        #pragma unroll
        for (int d = 0; d < 4; ++d) {
            union { _Float16 h[2]; int i; } u;
            u.h[0] = v[2 * d]; u.h[1] = v[2 * d + 1];
            F.i[d] = u.i;
        }
        wf[mt * 64 + lane] = F.q;
#endif
    }

    // ---- A2 Ah/Al frags (sigma2 row permutation; f16 2-term) ----
    // row j1v==63 carries bias2 (h1[63]==1): j2<25 -> fb2[j2]; j2==31 -> 1.0
    #pragma unroll
    for (int kt = 0; kt < 2; ++kt) {
        #pragma unroll
        for (int mt2 = 0; mt2 < 2; ++mt2) {
            int j2 = ((L >> 2) << 3) + (mt2 << 2) + (L & 3);
            float w[8];
            #pragma unroll
            for (int r = 0; r < 8; ++r) {
                int j1v = kt * 32 + 8 * g + r;
                float wv = 0.f;
                if (j1v < 50)       wv = (j2 < 25) ? fW2[j1v * 25 + j2] : 0.f;
                else if (j1v == 63) wv = (j2 < 25) ? fb2[j2] : (j2 == 31 ? 1.f : 0.f);
                w[r] = wv;
            }
            S8 H, Lo;
            #pragma unroll
            for (int d = 0; d < 4; ++d) split_pair_f16(w[2*d], w[2*d+1], H.i[d], Lo.i[d]);
            wf[(4 + kt * 2 + mt2) * 64 + lane] = H.q;
            wf[(8 + kt * 2 + mt2) * 64 + lane] = Lo.q;
        }
    }

    // ---- A3 Ah/Al frags ----
    // row j2v==31 carries bias3 (h2[31]==1): m<5 -> fb3[m]
    {
        int m = L;
        float w[8];
        #pragma unroll
        for (int r = 0; r < 8; ++r) {
            int j2v = 8 * g + r;
            float wv = 0.f;
            if (j2v < 25)       wv = (m < 5) ? fW3[j2v * 5 + m] : 0.f;
            else if (j2v == 31) wv = (m < 5) ? fb3[m] : 0.f;
            w[r] = wv;
        }
        S8 H, Lo;
        #pragma unroll
        for (int d = 0; d < 4; ++d) split_pair_f16(w[2*d], w[2*d+1], H.i[d], Lo.i[d]);
        wf[12 * 64 + lane] = H.q;
        wf[13 * 64 + lane] = Lo.q;
    }

    // ---- renormalized embedding: raw floats + f16 hi/lo dwords ----
    if (lane < 10) {
        float a0 = emb[2 * lane], a1 = emb[2 * lane + 1];
        float n = sqrtf(a0 * a0 + a1 * a1);
        float s = fminf(1.f, 1.f / fmaxf(n, 1e-7f));
        float e0 = a0 * s, e1 = a1 * s;
        int dh, dl;
        split_pair_f16(e0, e1, dh, dl);
        ws[WS_EMBH + lane] = dh;
        ws[WS_EMBL + lane] = dl;
        ((float*)ws)[WS_EMBR + 2 * lane] = e0;
        ((float*)ws)[WS_EMBR + 2 * lane + 1] = e1;
    }
}

// Two batch rows per block: waves 0,1 -> row0; waves 2,3 -> row1.
// Single-chain loop; B1 staged as 12B (3 dwords), ones dword is an immediate.
#if HAVE_MFMA16
__global__ __launch_bounds__(256, 5) void sp_main(
#else
__global__ __launch_bounds__(256, 4) void sp_main(
#endif
    const float* __restrict__ x_features,
    const float* __restrict__ features,
    const int* __restrict__ ws,
    const float* __restrict__ rW1, const float* __restrict__ rb1,
    const float* __restrict__ rW2, const float* __restrict__ rb2,
    const float* __restrict__ rW3, const float* __restrict__ rb3,
    float* __restrict__ out)
{
    __shared__ int2 embhl[16];
    __shared__ float embr[20];
    __shared__ int bs3[2][3 * LSEQ];     // 12B/frag; lane stride 3 dwords -> conflict-free
    __shared__ float redS[4][5], redM[4][5];
    __shared__ float hhs[2][14];
    __shared__ float r1buf[2][50];

    const int t = threadIdx.x;
    const int b = blockIdx.x;            // handles batch rows 2b, 2b+1
    const int lane = t & 63;
    const int wid = t >> 6;
    const int L = lane & 15;

    // ---- load prepacked A fragments (L2-broadcast); biases ride in A/B k-slots ----
    const int4* wf = (const int4*)ws;
#if HAVE_MFMA16
    S4 A1[4];
    #pragma unroll
    for (int f = 0; f < 4; ++f)  A1[f].q  = ((const int2*)ws)[f * 64 + lane];
#else
    S8 A1[4];
    #pragma unroll
    for (int f = 0; f < 4; ++f)  A1[f].q  = wf[f * 64 + lane];
#endif
    S8 A2H[4], A2L[4], A3H, A3L;
    #pragma unroll
    for (int f = 0; f < 4; ++f)  A2H[f].q = wf[(4 + f) * 64 + lane];
    #pragma unroll
    for (int f = 0; f < 4; ++f)  A2L[f].q = wf[(8 + f) * 64 + lane];
    A3H.q = wf[12 * 64 + lane];
    A3L.q = wf[13 * 64 + lane];

    if (t < 16) { embhl[t] = make_int2(ws[WS_EMBH + t], ws[WS_EMBL + t]); }
    if (t < 20) embr[t] = ((const float*)ws)[WS_EMBR + t];
    __syncthreads();

    // ---- stage BOTH rows' inputs as 12B B1 frags ----
    const float* f0 = features + (size_t)(2 * b) * (3 * LSEQ);
    #pragma unroll
    for (int r = 0; r < 2; ++r) {
        const float* fr = f0 + r * 3 * LSEQ;
        #pragma unroll
        for (int j = 0; j < 4; ++j) {
            const int p = t + 256 * j;
            float av = fr[p];
            float bv = fr[LSEQ + p];
            float cv = fr[2 * LSEQ + p];
            int2 e = embhl[(int)av];
            int* q = &bs3[r][3 * p];
            q[0] = e.x;
            q[1] = pack_f16(bv, cv);
            q[2] = e.y;
        }
    }
    __syncthreads();

    float rs[4] = {0.f, 0.f, 0.f, 0.f};
    float rm[4] = {-3.4e38f, -3.4e38f, -3.4e38f, -3.4e38f};
    const f32x4 kzero = {0.f, 0.f, 0.f, 0.f};

    const int wr = wid >> 1;            // this wave's row
    const int hw = wid & 1;             // which half of the row
    const int pbase = hw * 512 + L;
#if HAVE_MFMA16
    const bool podd = ((lane >> 4) & 1) != 0;
#endif

    // ---- single-chain main loop: 32 tiles per wave ----
    #pragma unroll 2
    for (int it = 0; it < 32; ++it) {
        const int* qa = &bs3[wr][3 * (pbase + it * 16)];
        int c0 = qa[0], c1 = qa[1], c2 = qa[2];

        // GEMM1
        f32x4 h1[4];
#if HAVE_MFMA16
        S4 B1;
        B1.i[0] = podd ? c2 : c0;             // odd k-groups: [el0,el1]; even: [eh0,eh1... wait]
        B1.i[1] = podd ? 0x00003C00 : c1;     // odd: [1,0]; even: [l0,l1]
        #pragma unroll
        for (int mt = 0; mt < 4; ++mt) h1[mt] = MFMA16(A1[mt].h, B1.h, kzero);
#else
        S8 B1;
        B1.i[0] = c0; B1.i[1] = c1; B1.i[2] = c2; B1.i[3] = 0x00003C00;
        #pragma unroll
        for (int mt = 0; mt < 4; ++mt) h1[mt] = MFMA(A1[mt].h, B1.h, kzero);
#endif

        // B2 frags: RTZ pack + packed relu, sigma1 D->k alignment (verified)
        S8 B20, B21;
        B20.i[0] = relu_pkrtz(h1[0][0], h1[0][1]);
        B20.i[1] = relu_pkrtz(h1[0][2], h1[0][3]);
        B20.i[2] = relu_pkrtz(h1[1][0], h1[1][1]);
        B20.i[3] = relu_pkrtz(h1[1][2], h1[1][3]);
        B21.i[0] = relu_pkrtz(h1[2][0], h1[2][1]);
        B21.i[1] = relu_pkrtz(h1[2][2], h1[2][3]);
        B21.i[2] = relu_pkrtz(h1[3][0], h1[3][1]);
        B21.i[3] = relu_pkrtz(h1[3][2], h1[3][3]);

        // GEMM2: 8 MFMAs (Ah+Al per kt); bias2 via A2 row 63 x h1[63]==1
        f32x4 h2[2];
        #pragma unroll
        for (int mt2 = 0; mt2 < 2; ++mt2) {
            f32x4 acc = kzero;
            acc = MFMA(A2H[mt2].h,     B20.h, acc);
            acc = MFMA(A2L[mt2].h,     B20.h, acc);
            acc = MFMA(A2H[2 + mt2].h, B21.h, acc);
            acc = MFMA(A2L[2 + mt2].h, B21.h, acc);
            h2[mt2] = acc;
        }

        // B3 frag
        S8 B3;
        B3.i[0] = relu_pkrtz(h2[0][0], h2[0][1]);
        B3.i[1] = relu_pkrtz(h2[0][2], h2[0][3]);
        B3.i[2] = relu_pkrtz(h2[1][0], h2[1][1]);
        B3.i[3] = relu_pkrtz(h2[1][2], h2[1][3]);

        // GEMM3: 2 MFMAs; bias3 via A3 row 31 x h2[31]==1
        f32x4 h3 = MFMA(A3H.h, B3.h, kzero);
        h3 = MFMA(A3L.h, B3.h, h3);

        #pragma unroll
        for (int r = 0; r < 4; ++r) {
            rs[r] += h3[r];
            rm[r] = fmaxf(rm[r], h3[r]);
        }
    }

    // ---- reduce over the 16 position-lanes within each 16-lane group ----
    #pragma unroll
    for (int off = 1; off <= 8; off <<= 1) {
        #pragma unroll
        for (int r = 0; r < 4; ++r) {
            rs[r] += __shfl_xor(rs[r], off);
            rm[r] = fmaxf(rm[r], __shfl_xor(rm[r], off));
        }
    }
    {
        const int kg = (lane >> 4);
        if (L == 0) {
            #pragma unroll
            for (int r = 0; r < 4; ++r) {
                int m = 4 * kg + r;
                if (m < 5) { redS[wid][m] = rs[r]; redM[wid][m] = rm[r]; }
            }
        }
    }
    __syncthreads();

    // ---- combine waves per row + build hh[2][14] ----
    if (t < 5) {
        hhs[0][t] = redS[0][t] + redS[1][t];
    } else if (t < 10) {
        hhs[0][t] = fmaxf(redM[0][t - 5], redM[1][t - 5]);
    } else if (t == 10) {
        int xa = (int)x_features[6 * b];
        hhs[0][10] = embr[2 * xa];
        hhs[0][11] = embr[2 * xa + 1];
        hhs[0][12] = x_features[6 * b + 1];
        hhs[0][13] = x_features[6 * b + 2];
    } else if (t >= 128 && t < 133) {
        hhs[1][t - 128] = redS[2][t - 128] + redS[3][t - 128];
    } else if (t >= 133 && t < 138) {
        hhs[1][t - 128] = fmaxf(redM[2][t - 133], redM[3][t - 133]);
    } else if (t == 138) {
        int xa = (int)x_features[6 * b + 3];
        hhs[1][10] = embr[2 * xa];
        hhs[1][11] = embr[2 * xa + 1];
        hhs[1][12] = x_features[6 * b + 4];
        hhs[1][13] = x_features[6 * b + 5];
    }
    __syncthreads();

    // ---- head MLPs in parallel: wave 0 -> row0, wave 2 -> row1 ----
    if (t < 50) {
        float acc = rb1[t];
        #pragma unroll
        for (int i = 0; i < 14; ++i) acc += hhs[0][i] * rW1[i * 50 + t];
        r1buf[0][t] = fmaxf(acc, 0.f);
    } else if (t >= 128 && t < 178) {
        int tt = t - 128;
        float acc = rb1[tt];
        #pragma unroll
        for (int i = 0; i < 14; ++i) acc += hhs[1][i] * rW1[i * 50 + tt];
        r1buf[1][tt] = fmaxf(acc, 0.f);
    }
    __syncthreads();

    float oacc = 0.f;
    if (t < 25) {
        float acc = rb2[t];
        #pragma unroll
        for (int k = 0; k < 50; ++k) acc += r1buf[0][k] * rW2[k * 25 + t];
        oacc = fmaxf(acc, 0.f) * rW3[t];
    } else if (t >= 128 && t < 153) {
        int tt = t - 128;
        float acc = rb2[tt];
        #pragma unroll
        for (int k = 0; k < 50; ++k) acc += r1buf[1][k] * rW2[k * 25 + tt];
        oacc = fmaxf(acc, 0.f) * rW3[tt];
    }
    if (t < 64 || (t >= 128 && t < 192)) {
        #pragma unroll
        for (int off = 32; off > 0; off >>= 1) oacc += __shfl_down(oacc, off);
    }
    if (t == 0)   out[2 * b]     = oacc + rb3[0];
    if (t == 128) out[2 * b + 1] = oacc + rb3[0];
}

extern "C" void kernel_launch(void* const* d_in, const int* in_sizes, int n_in,
                              void* d_out, int out_size, void* d_ws, size_t ws_size,
                              hipStream_t stream) {
    const float* x_features = (const float*)d_in[0];
    const float* features   = (const float*)d_in[1];
    // d_in[2] = lengths (dead in the math)
    const float* emb = (const float*)d_in[3];
    const float* fW1 = (const float*)d_in[4];
    const float* fb1 = (const float*)d_in[5];
    const float* fW2 = (const float*)d_in[6];
    const float* fb2 = (const float*)d_in[7];
    const float* fW3 = (const float*)d_in[8];
    const float* fb3 = (const float*)d_in[9];
    const float* rW1 = (const float*)d_in[10];
    const float* rb1 = (const float*)d_in[11];
    const float* rW2 = (const float*)d_in[12];
    const float* rb2 = (const float*)d_in[13];
    const float* rW3 = (const float*)d_in[14];
    const float* rb3 = (const float*)d_in[15];
    float* out = (float*)d_out;
    int* ws = (int*)d_ws;

    sp_prep<<<1, 64, 0, stream>>>(emb, fW1, fb1, fW2, fb2, fW3, fb3, ws);
    sp_main<<<BSZ / 2, 256, 0, stream>>>(x_features, features, ws,
                                         rW1, rb1, rW2, rb2, rW3, rb3, out);
}